// Round 1
// baseline (112.497 us; speedup 1.0000x reference)
//
#include <hip/hip_runtime.h>
#include <math.h>

#define B_ 8
#define C_ 256
#define C2_ 512
#define DK_ 32
#define HW_ 2304

// ws layout (floats):
//   [0,2048)      wq_eff [8][256]
//   [2048,4096)   vg     [8][256]
//   [4096,4104)   qb     [8]
//   [4104,4106)   lmin, lmax
//   [4352,22784)  a      [8][2304]
//   [22784,41216) s      [8][2304]
#define WS_WQ   0
#define WS_VG   2048
#define WS_QB   4096
#define WS_LMM  4104
#define WS_A    4352
#define WS_S    22784

__global__ __launch_bounds__(256) void k_prep(
    const float* __restrict__ text, const float* __restrict__ l,
    const float* __restrict__ Wg1,  const float* __restrict__ bg1,
    const float* __restrict__ ln_g, const float* __restrict__ ln_b,
    const float* __restrict__ Wg2,  const float* __restrict__ bg2,
    const float* __restrict__ Wq,   const float* __restrict__ bq,
    const float* __restrict__ Wk,   const float* __restrict__ Wv,
    float* __restrict__ ws)
{
    const int b = blockIdx.x;
    const int tid = threadIdx.x;

    if (b == B_) {
        // reduce min/max of l
        float mn = 1e30f, mx = -1e30f;
        for (int j = tid; j < HW_; j += 256) {
            float v = l[j];
            mn = fminf(mn, v); mx = fmaxf(mx, v);
        }
        __shared__ float smn[4], smx[4];
        for (int o = 32; o; o >>= 1) {
            mn = fminf(mn, __shfl_down(mn, o));
            mx = fmaxf(mx, __shfl_down(mx, o));
        }
        if ((tid & 63) == 0) { smn[tid >> 6] = mn; smx[tid >> 6] = mx; }
        __syncthreads();
        if (tid == 0) {
            mn = fminf(fminf(smn[0], smn[1]), fminf(smn[2], smn[3]));
            mx = fmaxf(fmaxf(smx[0], smx[1]), fmaxf(smx[2], smx[3]));
            ws[WS_LMM + 0] = mn; ws[WS_LMM + 1] = mx;
        }
        return;
    }

    __shared__ float tx[C_];
    __shared__ float tsh[C2_];
    __shared__ float gv[C_];
    __shared__ float kg[DK_];
    __shared__ float r1[4], r2[4];

    tx[tid] = text[b * C_ + tid];
    __syncthreads();

    // t = text @ Wg1 + bg1  (each thread: outputs tid, tid+256)
    float acc0 = bg1[tid], acc1 = bg1[tid + 256];
    #pragma unroll 4
    for (int c = 0; c < C_; ++c) {
        float t = tx[c];
        acc0 += t * Wg1[c * C2_ + tid];
        acc1 += t * Wg1[c * C2_ + tid + 256];
    }

    // LayerNorm over 512
    float s1 = acc0 + acc1;
    float s2 = acc0 * acc0 + acc1 * acc1;
    for (int o = 32; o; o >>= 1) {
        s1 += __shfl_down(s1, o);
        s2 += __shfl_down(s2, o);
    }
    if ((tid & 63) == 0) { r1[tid >> 6] = s1; r2[tid >> 6] = s2; }
    __syncthreads();
    s1 = r1[0] + r1[1] + r1[2] + r1[3];
    s2 = r2[0] + r2[1] + r2[2] + r2[3];
    const float mu = s1 * (1.0f / 512.0f);
    const float var = s2 * (1.0f / 512.0f) - mu * mu;
    const float rstd = rsqrtf(var + 1e-5f);

    // normalize, affine, exact GELU
    {
        float v0 = (acc0 - mu) * rstd * ln_g[tid] + ln_b[tid];
        float v1 = (acc1 - mu) * rstd * ln_g[tid + 256] + ln_b[tid + 256];
        tsh[tid]       = 0.5f * v0 * (1.0f + erff(v0 * 0.70710678118654752f));
        tsh[tid + 256] = 0.5f * v1 * (1.0f + erff(v1 * 0.70710678118654752f));
    }
    __syncthreads();

    // GvT = t @ Wg2 + bg2
    float g = bg2[tid];
    #pragma unroll 4
    for (int j = 0; j < C2_; ++j) g += tsh[j] * Wg2[j * C_ + tid];
    gv[tid] = g;
    __syncthreads();

    // kg[d] = sum_c Wk[d,c] * GvT[c]
    if (tid < DK_) {
        float acc = 0.f;
        for (int c = 0; c < C_; ++c) acc += Wk[tid * C_ + c] * gv[c];
        kg[tid] = acc;
    }
    __syncthreads();

    // vg[c] = sum_c' Wv[c,c'] * GvT[c']
    float vacc = 0.f;
    #pragma unroll 4
    for (int c = 0; c < C_; ++c) vacc += Wv[tid * C_ + c] * gv[c];
    ws[WS_VG + b * C_ + tid] = vacc;

    // wq_eff[c] = sum_d kg[d] * Wq[d,c]
    float w = 0.f;
    #pragma unroll
    for (int d = 0; d < DK_; ++d) w += kg[d] * Wq[d * C_ + tid];
    ws[WS_WQ + b * C_ + tid] = w;

    if (tid == 0) {
        float q = 0.f;
        for (int d = 0; d < DK_; ++d) q += kg[d] * bq[d];
        ws[WS_QB + b] = q;
    }
}

// a[b,i] = sum_c wq_eff[b,c] * img[b,c,i] + qb[b]
__global__ __launch_bounds__(256) void k_a(
    const float* __restrict__ img, float* __restrict__ ws)
{
    const int blk = blockIdx.x;          // 72 blocks = 8 b * 9 tiles
    const int b = blk / 9;
    const int i = (blk % 9) * 256 + threadIdx.x;
    __shared__ float wq[C_];
    wq[threadIdx.x] = ws[WS_WQ + b * C_ + threadIdx.x];
    __syncthreads();
    const float* x = img + (size_t)b * C_ * HW_ + i;
    float acc = ws[WS_QB + b];
    #pragma unroll 8
    for (int c = 0; c < C_; ++c) acc += wq[c] * x[(size_t)c * HW_];
    ws[WS_A + b * HW_ + i] = acc;
}

// s[p] = sum_j l[j]*exp(m*l[j]-mx) / sum_j exp(m*l[j]-mx),  m = a[p]
__global__ __launch_bounds__(256) void k_s(
    const float* __restrict__ l, float* __restrict__ ws)
{
    __shared__ float lsh[HW_];
    const int tid = threadIdx.x;
    #pragma unroll
    for (int j = tid; j < HW_; j += 256) lsh[j] = l[j];
    __syncthreads();

    const int p = blockIdx.x * 32 + (tid >> 3);   // 576 blocks * 32 pixels
    const int sub = tid & 7;
    const float m = ws[WS_A + p];
    const float lmin = ws[WS_LMM + 0], lmax = ws[WS_LMM + 1];
    const float mx = (m >= 0.f) ? m * lmax : m * lmin;

    float se = 0.f, sle = 0.f;
    #pragma unroll 4
    for (int j = sub; j < HW_; j += 8) {
        float lj = lsh[j];
        float e = __expf(m * lj - mx);
        se += e;
        sle += e * lj;
    }
    se  += __shfl_xor(se, 1);  sle += __shfl_xor(sle, 1);
    se  += __shfl_xor(se, 2);  sle += __shfl_xor(sle, 2);
    se  += __shfl_xor(se, 4);  sle += __shfl_xor(sle, 4);
    if (sub == 0) ws[WS_S + p] = sle / se;
}

// out[b,c,i] = img[b,c,i] + gamma*(vg[b,c]*s[b,i] + bv[c])
__global__ __launch_bounds__(256) void k_out(
    const float* __restrict__ img, const float* __restrict__ bv,
    const float* __restrict__ gamma, const float* __restrict__ ws,
    float* __restrict__ out)
{
    const float g = gamma[0];
    const size_t idx = (size_t)blockIdx.x * 256 + threadIdx.x;  // float4 index
    const size_t flat = idx * 4;
    const int b = (int)(flat / (C_ * HW_));
    const int rem = (int)(flat % (C_ * HW_));
    const int c = rem / HW_;
    const int i = rem % HW_;

    const float4 im = *(const float4*)(img + flat);
    const float4 s4 = *(const float4*)(ws + WS_S + b * HW_ + i);
    const float vgc = ws[WS_VG + b * C_ + c];
    const float bvc = bv[c];
    float4 o;
    o.x = im.x + g * (vgc * s4.x + bvc);
    o.y = im.y + g * (vgc * s4.y + bvc);
    o.z = im.z + g * (vgc * s4.z + bvc);
    o.w = im.w + g * (vgc * s4.w + bvc);
    *(float4*)(out + flat) = o;
}

extern "C" void kernel_launch(void* const* d_in, const int* in_sizes, int n_in,
                              void* d_out, int out_size, void* d_ws, size_t ws_size,
                              hipStream_t stream) {
    const float* img   = (const float*)d_in[0];
    const float* text  = (const float*)d_in[1];
    const float* l     = (const float*)d_in[2];
    const float* Wg1   = (const float*)d_in[3];
    const float* bg1   = (const float*)d_in[4];
    const float* ln_g  = (const float*)d_in[5];
    const float* ln_b  = (const float*)d_in[6];
    const float* Wg2   = (const float*)d_in[7];
    const float* bg2   = (const float*)d_in[8];
    const float* Wq    = (const float*)d_in[9];
    const float* bq    = (const float*)d_in[10];
    const float* Wk    = (const float*)d_in[11];
    // bk (d_in[12]) cancels in the softmax — unused
    const float* Wv    = (const float*)d_in[13];
    const float* bv    = (const float*)d_in[14];
    const float* gamma = (const float*)d_in[15];
    float* out = (float*)d_out;
    float* ws  = (float*)d_ws;

    k_prep<<<B_ + 1, 256, 0, stream>>>(text, l, Wg1, bg1, ln_g, ln_b,
                                       Wg2, bg2, Wq, bq, Wk, Wv, ws);
    k_a<<<B_ * (HW_ / 256), 256, 0, stream>>>(img, ws);
    k_s<<<(B_ * HW_) / 32, 256, 0, stream>>>(l, ws);
    k_out<<<(size_t)B_ * C_ * HW_ / 4 / 256, 256, 0, stream>>>(img, bv, gamma, ws, out);
}

// Round 2
// 56.737 us; speedup vs baseline: 1.9828x; 1.9828x over previous
//
#include <hip/hip_runtime.h>
#include <math.h>

#define B_ 8
#define C_ 256
#define C2_ 512
#define DK_ 32
#define HW_ 2304

// ws layout (floats):
#define WS_WQ   0        // wq_eff [8][256]
#define WS_VG   2048     // vg     [8][256]
#define WS_QB   4096     // qb     [8]
#define WS_LMM  4104     // lmin, lmax
#define WS_TP   4608     // t_pre  [8][512]
#define WS_GV   8704     // gv     [8][256]
#define WS_A    10752    // a      [8][2304]
#define WS_S    29184    // s      [8][2304]

__device__ __forceinline__ float gelu_exact(float x) {
    return 0.5f * x * (1.0f + erff(x * 0.70710678118654752f));
}

// t_pre[b][j] = sum_c text[b][c]*Wg1[c][j] + bg1[j];  block 128: l min/max
__global__ __launch_bounds__(256) void k_mlp1(
    const float* __restrict__ text, const float* __restrict__ l,
    const float* __restrict__ Wg1,  const float* __restrict__ bg1,
    float* __restrict__ ws)
{
    const int tid = threadIdx.x;
    if (blockIdx.x == 128) {
        float mn = 1e30f, mx = -1e30f;
        for (int j = tid; j < HW_; j += 256) {
            float v = l[j];
            mn = fminf(mn, v); mx = fmaxf(mx, v);
        }
        __shared__ float smn[4], smx[4];
        for (int o = 32; o; o >>= 1) {
            mn = fminf(mn, __shfl_down(mn, o));
            mx = fmaxf(mx, __shfl_down(mx, o));
        }
        if ((tid & 63) == 0) { smn[tid >> 6] = mn; smx[tid >> 6] = mx; }
        __syncthreads();
        if (tid == 0) {
            mn = fminf(fminf(smn[0], smn[1]), fminf(smn[2], smn[3]));
            mx = fmaxf(fmaxf(smx[0], smx[1]), fmaxf(smx[2], smx[3]));
            ws[WS_LMM + 0] = mn; ws[WS_LMM + 1] = mx;
        }
        return;
    }
    const int b = blockIdx.x >> 4;
    const int tile = blockIdx.x & 15;          // 16 tiles of 32 output cols
    __shared__ float tx[C_];
    __shared__ float part[8][32];
    tx[tid] = text[b * C_ + tid];
    __syncthreads();
    const int jj = tid & 31, sub = tid >> 5;   // 8 lanes per output col
    const int j = tile * 32 + jj;
    const float* wcol = Wg1 + (size_t)(sub * 32) * C2_ + j;
    float acc = 0.f;
    #pragma unroll 8
    for (int k = 0; k < 32; ++k)
        acc += tx[sub * 32 + k] * wcol[(size_t)k * C2_];
    part[sub][jj] = acc;
    __syncthreads();
    if (tid < 32) {
        float s = bg1[tile * 32 + tid];
        #pragma unroll
        for (int u = 0; u < 8; ++u) s += part[u][tid];
        ws[WS_TP + b * C2_ + tile * 32 + tid] = s;
    }
}

// gv[b][j] = GELU(LN(t_pre))[b] @ Wg2[:,j] + bg2[j]   (LN recomputed per block)
__global__ __launch_bounds__(256) void k_mlp2(
    const float* __restrict__ ln_g, const float* __restrict__ ln_b,
    const float* __restrict__ Wg2,  const float* __restrict__ bg2,
    float* __restrict__ ws)
{
    const int b = blockIdx.x >> 3;
    const int tile = blockIdx.x & 7;           // 8 tiles of 32 output cols
    const int tid = threadIdx.x;
    __shared__ float tsh[C2_];
    __shared__ float r1[4], r2[4];
    __shared__ float part[8][32];

    float v0 = ws[WS_TP + b * C2_ + tid];
    float v1 = ws[WS_TP + b * C2_ + tid + 256];
    float s1 = v0 + v1, s2 = v0 * v0 + v1 * v1;
    for (int o = 32; o; o >>= 1) {
        s1 += __shfl_down(s1, o);
        s2 += __shfl_down(s2, o);
    }
    if ((tid & 63) == 0) { r1[tid >> 6] = s1; r2[tid >> 6] = s2; }
    __syncthreads();
    s1 = r1[0] + r1[1] + r1[2] + r1[3];
    s2 = r2[0] + r2[1] + r2[2] + r2[3];
    const float mu = s1 * (1.0f / 512.0f);
    const float rstd = rsqrtf(s2 * (1.0f / 512.0f) - mu * mu + 1e-5f);
    tsh[tid]       = gelu_exact((v0 - mu) * rstd * ln_g[tid] + ln_b[tid]);
    tsh[tid + 256] = gelu_exact((v1 - mu) * rstd * ln_g[tid + 256] + ln_b[tid + 256]);
    __syncthreads();

    const int jj = tid & 31, sub = tid >> 5;   // 8 lanes x 64 MACs
    const int j = tile * 32 + jj;
    const float* wcol = Wg2 + (size_t)(sub * 64) * C_ + j;
    float acc = 0.f;
    #pragma unroll 8
    for (int k = 0; k < 64; ++k)
        acc += tsh[sub * 64 + k] * wcol[(size_t)k * C_];
    part[sub][jj] = acc;
    __syncthreads();
    if (tid < 32) {
        float s = bg2[tile * 32 + tid];
        #pragma unroll
        for (int u = 0; u < 8; ++u) s += part[u][tid];
        ws[WS_GV + b * C_ + tile * 32 + tid] = s;
    }
}

// vg[b][o] = Wv[o,:]·gv[b];  tile0 additionally: kg, wq_eff, qb
__global__ __launch_bounds__(256) void k_proj(
    const float* __restrict__ Wq, const float* __restrict__ bq,
    const float* __restrict__ Wk, const float* __restrict__ Wv,
    float* __restrict__ ws)
{
    const int b = blockIdx.x >> 3;
    const int tile = blockIdx.x & 7;           // 8 tiles of 32 output rows
    const int tid = threadIdx.x;
    __shared__ __align__(16) float gvs[C_];
    __shared__ float kg[DK_];
    gvs[tid] = ws[WS_GV + b * C_ + tid];
    __syncthreads();

    const int o = tid >> 3, sub = tid & 7;     // 32 rows x 8 lanes
    const float4* grp = (const float4*)gvs + sub * 8;
    {
        const float4* wrow = (const float4*)(Wv + (size_t)(tile * 32 + o) * C_) + sub * 8;
        float acc = 0.f;
        #pragma unroll
        for (int k4 = 0; k4 < 8; ++k4) {
            float4 w4 = wrow[k4], g4 = grp[k4];
            acc += w4.x * g4.x + w4.y * g4.y + w4.z * g4.z + w4.w * g4.w;
        }
        acc += __shfl_xor(acc, 1);
        acc += __shfl_xor(acc, 2);
        acc += __shfl_xor(acc, 4);
        if (sub == 0) ws[WS_VG + b * C_ + tile * 32 + o] = acc;
    }
    if (tile == 0) {
        // kg[d] = Wk[d,:]·gv   (o plays role of d)
        const float4* wrow = (const float4*)(Wk + (size_t)o * C_) + sub * 8;
        float acc = 0.f;
        #pragma unroll
        for (int k4 = 0; k4 < 8; ++k4) {
            float4 w4 = wrow[k4], g4 = grp[k4];
            acc += w4.x * g4.x + w4.y * g4.y + w4.z * g4.z + w4.w * g4.w;
        }
        acc += __shfl_xor(acc, 1);
        acc += __shfl_xor(acc, 2);
        acc += __shfl_xor(acc, 4);
        if (sub == 0) kg[o] = acc;
        __syncthreads();
        float w = 0.f;
        #pragma unroll
        for (int d = 0; d < DK_; ++d) w += kg[d] * Wq[(size_t)d * C_ + tid];
        ws[WS_WQ + b * C_ + tid] = w;
        if (tid == 0) {
            float q = 0.f;
            for (int d = 0; d < DK_; ++d) q += kg[d] * bq[d];
            ws[WS_QB + b] = q;
        }
    }
}

// a[b,i] = sum_c wq_eff[b,c] * img[b,c,i] + qb[b]
__global__ __launch_bounds__(256) void k_a(
    const float* __restrict__ img, float* __restrict__ ws)
{
    const int blk = blockIdx.x;          // 72 blocks = 8 b * 9 tiles
    const int b = blk / 9;
    const int i = (blk % 9) * 256 + threadIdx.x;
    __shared__ float wq[C_];
    wq[threadIdx.x] = ws[WS_WQ + b * C_ + threadIdx.x];
    __syncthreads();
    const float* x = img + (size_t)b * C_ * HW_ + i;
    float acc = ws[WS_QB + b];
    #pragma unroll 8
    for (int c = 0; c < C_; ++c) acc += wq[c] * x[(size_t)c * HW_];
    ws[WS_A + b * HW_ + i] = acc;
}

// s[p] = sum_j l[j]*exp(m*l[j]-mx) / sum_j exp(m*l[j]-mx),  m = a[p]
__global__ __launch_bounds__(256) void k_s(
    const float* __restrict__ l, float* __restrict__ ws)
{
    __shared__ float lsh[HW_];
    const int tid = threadIdx.x;
    #pragma unroll
    for (int j = tid; j < HW_; j += 256) lsh[j] = l[j];
    __syncthreads();

    const int p = blockIdx.x * 32 + (tid >> 3);   // 576 blocks * 32 pixels
    const int sub = tid & 7;
    const float m = ws[WS_A + p];
    const float lmin = ws[WS_LMM + 0], lmax = ws[WS_LMM + 1];
    const float mx = (m >= 0.f) ? m * lmax : m * lmin;

    float se = 0.f, sle = 0.f;
    #pragma unroll 4
    for (int j = sub; j < HW_; j += 8) {
        float lj = lsh[j];
        float e = __expf(m * lj - mx);
        se += e;
        sle += e * lj;
    }
    se  += __shfl_xor(se, 1);  sle += __shfl_xor(sle, 1);
    se  += __shfl_xor(se, 2);  sle += __shfl_xor(sle, 2);
    se  += __shfl_xor(se, 4);  sle += __shfl_xor(sle, 4);
    if (sub == 0) ws[WS_S + p] = sle / se;
}

// out[b,c,i] = img[b,c,i] + gamma*(vg[b,c]*s[b,i] + bv[c])
__global__ __launch_bounds__(256) void k_out(
    const float* __restrict__ img, const float* __restrict__ bv,
    const float* __restrict__ gamma, const float* __restrict__ ws,
    float* __restrict__ out)
{
    const float g = gamma[0];
    const size_t idx = (size_t)blockIdx.x * 256 + threadIdx.x;  // float4 index
    const size_t flat = idx * 4;
    const int b = (int)(flat / (C_ * HW_));
    const int rem = (int)(flat % (C_ * HW_));
    const int c = rem / HW_;
    const int i = rem % HW_;

    const float4 im = *(const float4*)(img + flat);
    const float4 s4 = *(const float4*)(ws + WS_S + b * HW_ + i);
    const float vgc = ws[WS_VG + b * C_ + c];
    const float bvc = bv[c];
    float4 o;
    o.x = im.x + g * (vgc * s4.x + bvc);
    o.y = im.y + g * (vgc * s4.y + bvc);
    o.z = im.z + g * (vgc * s4.z + bvc);
    o.w = im.w + g * (vgc * s4.w + bvc);
    *(float4*)(out + flat) = o;
}

extern "C" void kernel_launch(void* const* d_in, const int* in_sizes, int n_in,
                              void* d_out, int out_size, void* d_ws, size_t ws_size,
                              hipStream_t stream) {
    const float* img   = (const float*)d_in[0];
    const float* text  = (const float*)d_in[1];
    const float* l     = (const float*)d_in[2];
    const float* Wg1   = (const float*)d_in[3];
    const float* bg1   = (const float*)d_in[4];
    const float* ln_g  = (const float*)d_in[5];
    const float* ln_b  = (const float*)d_in[6];
    const float* Wg2   = (const float*)d_in[7];
    const float* bg2   = (const float*)d_in[8];
    const float* Wq    = (const float*)d_in[9];
    const float* bq    = (const float*)d_in[10];
    const float* Wk    = (const float*)d_in[11];
    // bk (d_in[12]) cancels in the softmax — unused
    const float* Wv    = (const float*)d_in[13];
    const float* bv    = (const float*)d_in[14];
    const float* gamma = (const float*)d_in[15];
    float* out = (float*)d_out;
    float* ws  = (float*)d_ws;

    k_mlp1<<<129, 256, 0, stream>>>(text, l, Wg1, bg1, ws);
    k_mlp2<<<64, 256, 0, stream>>>(ln_g, ln_b, Wg2, bg2, ws);
    k_proj<<<64, 256, 0, stream>>>(Wq, bq, Wk, Wv, ws);
    k_a<<<B_ * (HW_ / 256), 256, 0, stream>>>(img, ws);
    k_s<<<(B_ * HW_) / 32, 256, 0, stream>>>(l, ws);
    k_out<<<(size_t)B_ * C_ * HW_ / 4 / 256, 256, 0, stream>>>(img, bv, gamma, ws, out);
}